// Round 7
// baseline (68.688 us; speedup 1.0000x reference)
//
#include <hip/hip_runtime.h>

#define MTOT 8192
#define NTOT 8192
#define DD   64
#define SPLIT (MTOT * DD)   // 524288 elems per hi/lo array

typedef __bf16 bf16x8 __attribute__((ext_vector_type(8)));
typedef float  f32x16 __attribute__((ext_vector_type(16)));
typedef unsigned short u16;
typedef unsigned short u16x4 __attribute__((ext_vector_type(4)));
typedef unsigned short u16x8 __attribute__((ext_vector_type(8)));

__device__ __forceinline__ u16 bf16_rne(float v) {
    unsigned int u = __float_as_uint(v);
    u = u + 0x7FFFu + ((u >> 16) & 1u);
    return (u16)(u >> 16);
}
__device__ __forceinline__ float bf16_to_f32(u16 h) {
    return __uint_as_float(((unsigned int)h) << 16);
}

#define MFMA(a, b, c) __builtin_amdgcn_mfma_f32_32x32x16_bf16((a), (b), (c), 0, 0, 0)

// ============ pre-pass: fp32 -> hi/lo bf16 in FRAGMENT-LINEAR order + norms ============
// elem(row,k) -> [(tt*4 + ks)*64 + lane]*8 + slot ; tt=row>>5, ks=k>>4,
// lane=(row&31)|(((k>>3)&1)<<5), slot=k&7.
__global__ __launch_bounds__(256)
void rbf_pre_kernel(const float* __restrict__ X, const float* __restrict__ Y,
                    u16* __restrict__ XhiF, u16* __restrict__ XloF,
                    u16* __restrict__ YhiF, u16* __restrict__ YloF,
                    float* __restrict__ xqs, float* __restrict__ yqs)
{
    const int gid = blockIdx.x * 256 + threadIdx.x;
    const int mat = gid >> 15;            // 0 = X, 1 = Y
    const int r4  = gid & 32767;
    const int row = r4 >> 2;
    const int q   = r4 & 3;               // == ks
    const float* src = mat ? Y : X;
    u16* hi  = mat ? YhiF : XhiF;
    u16* lo  = mat ? YloF : XloF;
    float* nrm = mat ? yqs : xqs;

    const long rbase = (long)row * DD + q * 16;
    float s = 0.f;
    u16x8 h0, h1, l0, l1;
    #pragma unroll
    for (int c = 0; c < 4; ++c) {
        const float4 v = *reinterpret_cast<const float4*>(src + rbase + c * 4);
        const float vv[4] = {v.x, v.y, v.z, v.w};
        #pragma unroll
        for (int e = 0; e < 4; ++e) {
            const int idx = c * 4 + e;
            const float x = vv[e];
            s = fmaf(x, x, s);
            const u16 hh = bf16_rne(x);
            const u16 ll = bf16_rne(x - bf16_to_f32(hh));
            if (idx < 8) { h0[idx] = hh; l0[idx] = ll; }
            else         { h1[idx - 8] = hh; l1[idx - 8] = ll; }
        }
    }
    s += __shfl_xor(s, 1);
    s += __shfl_xor(s, 2);
    if (q == 0) nrm[row] = s;

    const int tt = row >> 5, lr = row & 31;
    const long fbase = (long)(tt * 4 + q) * 512;
    *reinterpret_cast<u16x8*>(hi + fbase + lr * 8)        = h0;
    *reinterpret_cast<u16x8*>(hi + fbase + (32 + lr) * 8) = h1;
    *reinterpret_cast<u16x8*>(lo + fbase + lr * 8)        = l0;
    *reinterpret_cast<u16x8*>(lo + fbase + (32 + lr) * 8) = l1;
}

// ============ main: ZERO-LDS, ZERO-BARRIER. Fragments straight from global. ============
// 4096 blocks x 256 threads = 4 fully independent waves; wave w owns the
// (mt0, nt0) 64x64 quadrant of a 128x128 tile. Fragment-linear arrays make
// every wave fragment load one contiguous 1KB segment (L1/L2-hot).
// ks-level register double-buffering hides L1/L2 latency under 12 MFMAs.
__global__ __launch_bounds__(256, 3)
void rbf_nolds_kernel(const u16* __restrict__ XhiF, const u16* __restrict__ XloF,
                      const u16* __restrict__ YhiF, const u16* __restrict__ YloF,
                      const float* __restrict__ xqs, const float* __restrict__ yqs,
                      const float* __restrict__ gamma_p,
                      float* __restrict__ out)
{
    const int t = threadIdx.x;
    const int w = t >> 6;
    const int l = t & 63;
    const int loff = l * 8;

    // bijective XCD swizzle: each XCD gets 8 contiguous bm rows -> X panels
    // (0.5 MB) + all Y panels (2 MB) fit its 4 MB L2. NT stores don't pollute.
    const int bid = blockIdx.x;
    const int swz = ((bid & 7) << 9) | (bid >> 3);
    const int bm = swz >> 6;
    const int bn = swz & 63;
    const long row0 = (long)bm * 128;
    const long col0 = (long)bn * 128;

    const int mt0 = (w >> 1) * 2;
    const int nt0 = (w & 1) * 2;

    const u16* const xh = XhiF + (long)bm * 8192;
    const u16* const xl = XloF + (long)bm * 8192;
    const u16* const yh = YhiF + (long)bn * 8192;
    const u16* const yl = YloF + (long)bn * 8192;

#define FRAG(base, tt, ks) (*reinterpret_cast<const bf16x8*>((base) + ((tt) * 4 + (ks)) * 512 + loff))

    f32x16 acc[2][2];
    #pragma unroll
    for (int ii = 0; ii < 2; ++ii)
        #pragma unroll
        for (int jj = 0; jj < 2; ++jj)
            #pragma unroll
            for (int r = 0; r < 16; ++r) acc[ii][jj][r] = 0.f;

    // preload ks = 0
    bf16x8 cAH0 = FRAG(xh, mt0 + 0, 0), cAH1 = FRAG(xh, mt0 + 1, 0);
    bf16x8 cAL0 = FRAG(xl, mt0 + 0, 0), cAL1 = FRAG(xl, mt0 + 1, 0);
    bf16x8 cBH0 = FRAG(yh, nt0 + 0, 0), cBH1 = FRAG(yh, nt0 + 1, 0);
    bf16x8 cBL0 = FRAG(yl, nt0 + 0, 0), cBL1 = FRAG(yl, nt0 + 1, 0);

    #pragma unroll
    for (int ks = 0; ks < 4; ++ks) {
        bf16x8 nAH0, nAH1, nAL0, nAL1, nBH0, nBH1, nBL0, nBL1;
        if (ks < 3) {   // issue next-ks loads before the MFMA burst
            nAH0 = FRAG(xh, mt0 + 0, ks + 1); nAH1 = FRAG(xh, mt0 + 1, ks + 1);
            nAL0 = FRAG(xl, mt0 + 0, ks + 1); nAL1 = FRAG(xl, mt0 + 1, ks + 1);
            nBH0 = FRAG(yh, nt0 + 0, ks + 1); nBH1 = FRAG(yh, nt0 + 1, ks + 1);
            nBL0 = FRAG(yl, nt0 + 0, ks + 1); nBL1 = FRAG(yl, nt0 + 1, ks + 1);
        }
        acc[0][0] = MFMA(cAH0, cBH0, acc[0][0]);
        acc[0][1] = MFMA(cAH0, cBH1, acc[0][1]);
        acc[1][0] = MFMA(cAH1, cBH0, acc[1][0]);
        acc[1][1] = MFMA(cAH1, cBH1, acc[1][1]);
        acc[0][0] = MFMA(cAH0, cBL0, acc[0][0]);
        acc[0][1] = MFMA(cAH0, cBL1, acc[0][1]);
        acc[1][0] = MFMA(cAH1, cBL0, acc[1][0]);
        acc[1][1] = MFMA(cAH1, cBL1, acc[1][1]);
        acc[0][0] = MFMA(cAL0, cBH0, acc[0][0]);
        acc[0][1] = MFMA(cAL0, cBH1, acc[0][1]);
        acc[1][0] = MFMA(cAL1, cBH0, acc[1][0]);
        acc[1][1] = MFMA(cAL1, cBH1, acc[1][1]);
        if (ks < 3) {
            cAH0 = nAH0; cAH1 = nAH1; cAL0 = nAL0; cAL1 = nAL1;
            cBH0 = nBH0; cBH1 = nBH1; cBL0 = nBL0; cBL1 = nBL1;
        }
    }
#undef FRAG

    // ---- epilogue: arg = -g*(xq+yq-2*dot) clamped <= 0; NT-store exp ----
    // C/D (verified): m-row = (r&3)+8*(r>>2)+4*(l>>5) [+mt*32], n-col = l&31 [+nt*32]
    const float g  = gamma_p[0];
    const float g2 = 2.0f * g;
    const int l5x4 = (l >> 5) * 4;
    const int  ln  = l & 31;

    #pragma unroll
    for (int ii = 0; ii < 2; ++ii) {
        const int mt = mt0 + ii;
        float xv[16];
        #pragma unroll
        for (int q4 = 0; q4 < 4; ++q4) {
            const float4 x4 = *reinterpret_cast<const float4*>(
                xqs + row0 + mt * 32 + 8 * q4 + l5x4);
            xv[q4 * 4 + 0] = x4.x; xv[q4 * 4 + 1] = x4.y;
            xv[q4 * 4 + 2] = x4.z; xv[q4 * 4 + 3] = x4.w;
        }
        float* const orow = out + (row0 + mt * 32) * (long)NTOT;
        #pragma unroll
        for (int jj = 0; jj < 2; ++jj) {
            const long gc = col0 + (nt0 + jj) * 32 + ln;
            const float cy = -g * yqs[gc];
            #pragma unroll
            for (int r = 0; r < 16; ++r) {
                float arg = fmaf(g2, acc[ii][jj][r], fmaf(-g, xv[r], cy));
                arg = fminf(arg, 0.f);
                const int rr = (r & 3) + 8 * (r >> 2) + l5x4;
                __builtin_nontemporal_store(__expf(arg), orow + rr * (long)NTOT + gc);
            }
        }
    }
}

// ============ fallback (R2-style, known-good) if ws too small ============
__global__ __launch_bounds__(256, 2)
void rbf_fallback_kernel(const float* __restrict__ X,
                         const float* __restrict__ Y,
                         const float* __restrict__ gamma_p,
                         float* __restrict__ out)
{
    __shared__ unsigned short XfH[4][4][64][8];
    __shared__ unsigned short XfL[4][4][64][8];
    __shared__ unsigned short YfH[4][4][64][8];
    __shared__ unsigned short YfL[4][4][64][8];
    __shared__ float xq[128];
    __shared__ float yq[128];

    const int t = threadIdx.x;
    const long row0 = (long)blockIdx.y * 128;
    const long col0 = (long)blockIdx.x * 128;

    {
        const int k0   = (t & 15) * 4;
        const int ks   = k0 >> 4;
        const int l32  = ((k0 >> 3) & 1) << 5;
        const int slot = k0 & 4;
        #pragma unroll
        for (int i = 0; i < 8; ++i) {
            const int row  = (t >> 4) + i * 16;
            const int mt   = row >> 5;
            const int lane = (row & 31) | l32;
            const float4 vx = *reinterpret_cast<const float4*>(X + (row0 + row) * DD + k0);
            const float4 vy = *reinterpret_cast<const float4*>(Y + (col0 + row) * DD + k0);
            float xv[4] = {vx.x, vx.y, vx.z, vx.w};
            float yv[4] = {vy.x, vy.y, vy.z, vy.w};
            u16x4 xh, xl, yh, yl;
            #pragma unroll
            for (int e = 0; e < 4; ++e) {
                const u16 hx = bf16_rne(xv[e]);
                xh[e] = hx; xl[e] = bf16_rne(xv[e] - bf16_to_f32(hx));
                const u16 hy = bf16_rne(yv[e]);
                yh[e] = hy; yl[e] = bf16_rne(yv[e] - bf16_to_f32(hy));
            }
            *reinterpret_cast<u16x4*>(&XfH[mt][ks][lane][slot]) = xh;
            *reinterpret_cast<u16x4*>(&XfL[mt][ks][lane][slot]) = xl;
            *reinterpret_cast<u16x4*>(&YfH[mt][ks][lane][slot]) = yh;
            *reinterpret_cast<u16x4*>(&YfL[mt][ks][lane][slot]) = yl;
        }
    }
    {
        const int r = t & 127;
        const float* p2 = (t < 128) ? (X + (row0 + r) * DD) : (Y + (col0 + r) * DD);
        float s0 = 0.f, s1 = 0.f, s2 = 0.f, s3 = 0.f;
        #pragma unroll
        for (int c = 0; c < 16; ++c) {
            const float4 v = reinterpret_cast<const float4*>(p2)[c];
            s0 = fmaf(v.x, v.x, s0); s1 = fmaf(v.y, v.y, s1);
            s2 = fmaf(v.z, v.z, s2); s3 = fmaf(v.w, v.w, s3);
        }
        const float s = (s0 + s1) + (s2 + s3);
        if (t < 128) xq[r] = s; else yq[r] = s;
    }
    __syncthreads();

    const int w = t >> 6;
    const int l = t & 63;
    const int mt0 = (w >> 1) * 2;
    const int nt0 = (w & 1) * 2;

    bf16x8 aH[2][4], aL[2][4];
    #pragma unroll
    for (int i = 0; i < 2; ++i)
        #pragma unroll
        for (int ks = 0; ks < 4; ++ks) {
            aH[i][ks] = *reinterpret_cast<const bf16x8*>(&XfH[mt0 + i][ks][l][0]);
            aL[i][ks] = *reinterpret_cast<const bf16x8*>(&XfL[mt0 + i][ks][l][0]);
        }

    f32x16 acc[2][2];
    #pragma unroll
    for (int i = 0; i < 2; ++i)
        #pragma unroll
        for (int j = 0; j < 2; ++j)
            #pragma unroll
            for (int r = 0; r < 16; ++r) acc[i][j][r] = 0.f;

    #pragma unroll
    for (int ks = 0; ks < 4; ++ks) {
        const bf16x8 b0h = *reinterpret_cast<const bf16x8*>(&YfH[nt0 + 0][ks][l][0]);
        const bf16x8 b1h = *reinterpret_cast<const bf16x8*>(&YfH[nt0 + 1][ks][l][0]);
        const bf16x8 b0l = *reinterpret_cast<const bf16x8*>(&YfL[nt0 + 0][ks][l][0]);
        const bf16x8 b1l = *reinterpret_cast<const bf16x8*>(&YfL[nt0 + 1][ks][l][0]);
        acc[0][0] = MFMA(aH[0][ks], b0h, acc[0][0]);
        acc[0][1] = MFMA(aH[0][ks], b1h, acc[0][1]);
        acc[1][0] = MFMA(aH[1][ks], b0h, acc[1][0]);
        acc[1][1] = MFMA(aH[1][ks], b1h, acc[1][1]);
        acc[0][0] = MFMA(aH[0][ks], b0l, acc[0][0]);
        acc[0][1] = MFMA(aH[0][ks], b1l, acc[0][1]);
        acc[1][0] = MFMA(aH[1][ks], b0l, acc[1][0]);
        acc[1][1] = MFMA(aH[1][ks], b1l, acc[1][1]);
        acc[0][0] = MFMA(aL[0][ks], b0h, acc[0][0]);
        acc[0][1] = MFMA(aL[0][ks], b1h, acc[0][1]);
        acc[1][0] = MFMA(aL[1][ks], b0h, acc[1][0]);
        acc[1][1] = MFMA(aL[1][ks], b1h, acc[1][1]);
    }

    const float g = gamma_p[0];
    const int l5x4 = (l >> 5) * 4;
    const int ln = l & 31;
    #pragma unroll
    for (int i = 0; i < 2; ++i) {
        const int mt = mt0 + i;
        float xv[16];
        #pragma unroll
        for (int r = 0; r < 16; ++r)
            xv[r] = xq[mt * 32 + (r & 3) + 8 * (r >> 2) + l5x4];
        #pragma unroll
        for (int j = 0; j < 2; ++j) {
            const int nt = nt0 + j;
            const float yv = yq[nt * 32 + ln];
            const long gr = row0 + mt * 32;
            const long gc = col0 + nt * 32 + ln;
            #pragma unroll
            for (int r = 0; r < 16; ++r) {
                float s = fmaf(-2.f, acc[i][j][r], xv[r] + yv);
                s = fmaxf(s, 0.f);
                const long rr = gr + (r & 3) + 8 * (r >> 2) + l5x4;
                out[rr * NTOT + gc] = __expf(-g * s);
            }
        }
    }
}

extern "C" void kernel_launch(void* const* d_in, const int* in_sizes, int n_in,
                              void* d_out, int out_size, void* d_ws, size_t ws_size,
                              hipStream_t stream) {
    (void)in_sizes; (void)n_in; (void)out_size;
    const float* X = (const float*)d_in[0];
    const float* Y = (const float*)d_in[1];
    const float* gamma_p = (const float*)d_in[2];
    float* out = (float*)d_out;

    const size_t need = 4 * (size_t)SPLIT * sizeof(u16) + (MTOT + NTOT) * sizeof(float);

    if (ws_size >= need) {
        u16* XhiF = (u16*)d_ws;
        u16* XloF = XhiF + SPLIT;
        u16* YhiF = XloF + SPLIT;
        u16* YloF = YhiF + SPLIT;
        float* xqs = (float*)(YloF + SPLIT);
        float* yqs = xqs + MTOT;
        rbf_pre_kernel<<<256, 256, 0, stream>>>(X, Y, XhiF, XloF, YhiF, YloF, xqs, yqs);
        rbf_nolds_kernel<<<4096, 256, 0, stream>>>(XhiF, XloF, YhiF, YloF, xqs, yqs, gamma_p, out);
    } else {
        dim3 grid(NTOT / 128, MTOT / 128);
        rbf_fallback_kernel<<<grid, 256, 0, stream>>>(X, Y, gamma_p, out);
    }
}

// Round 8
// 57.436 us; speedup vs baseline: 1.1959x; 1.1959x over previous
//
#include <hip/hip_runtime.h>

#define MTOT 8192
#define NTOT 8192
#define DD   64
#define SPLIT (MTOT * DD)   // 524288 elems per hi/lo array

typedef __bf16 bf16x8 __attribute__((ext_vector_type(8)));
typedef float  f32x16 __attribute__((ext_vector_type(16)));
typedef unsigned short u16;
typedef unsigned short u16x4 __attribute__((ext_vector_type(4)));
typedef unsigned short u16x8 __attribute__((ext_vector_type(8)));

__device__ __forceinline__ u16 bf16_rne(float v) {
    unsigned int u = __float_as_uint(v);
    u = u + 0x7FFFu + ((u >> 16) & 1u);
    return (u16)(u >> 16);
}
__device__ __forceinline__ float bf16_to_f32(u16 h) {
    return __uint_as_float(((unsigned int)h) << 16);
}

#define MFMA(a, b, c) __builtin_amdgcn_mfma_f32_32x32x16_bf16((a), (b), (c), 0, 0, 0)

// async 16B/lane global -> LDS (wave-uniform LDS base, per-lane global addr)
__device__ __forceinline__ void load_lds_16B(const u16* g, u16* lds_uniform) {
    __builtin_amdgcn_global_load_lds(
        (const __attribute__((address_space(1))) unsigned int*)g,
        (__attribute__((address_space(3))) unsigned int*)lds_uniform,
        16, 0, 0);
}

// ============ pre-pass: fp32 -> hi/lo bf16 in FRAGMENT-LINEAR order + norms ============
// elem(row,k) -> [(tt*4 + ks)*64 + lane]*8 + slot ; tt=row>>5, ks=k>>4,
// lane=(row&31)|(((k>>3)&1)<<5), slot=k&7.
__global__ __launch_bounds__(256)
void rbf_pre_kernel(const float* __restrict__ X, const float* __restrict__ Y,
                    u16* __restrict__ XhiF, u16* __restrict__ XloF,
                    u16* __restrict__ YhiF, u16* __restrict__ YloF,
                    float* __restrict__ xqs, float* __restrict__ yqs)
{
    const int gid = blockIdx.x * 256 + threadIdx.x;
    const int mat = gid >> 15;            // 0 = X, 1 = Y
    const int r4  = gid & 32767;
    const int row = r4 >> 2;
    const int q   = r4 & 3;               // == ks
    const float* src = mat ? Y : X;
    u16* hi  = mat ? YhiF : XhiF;
    u16* lo  = mat ? YloF : XloF;
    float* nrm = mat ? yqs : xqs;

    const long rbase = (long)row * DD + q * 16;
    float s = 0.f;
    u16x8 h0, h1, l0, l1;
    #pragma unroll
    for (int c = 0; c < 4; ++c) {
        const float4 v = *reinterpret_cast<const float4*>(src + rbase + c * 4);
        const float vv[4] = {v.x, v.y, v.z, v.w};
        #pragma unroll
        for (int e = 0; e < 4; ++e) {
            const int idx = c * 4 + e;
            const float x = vv[e];
            s = fmaf(x, x, s);
            const u16 hh = bf16_rne(x);
            const u16 ll = bf16_rne(x - bf16_to_f32(hh));
            if (idx < 8) { h0[idx] = hh; l0[idx] = ll; }
            else         { h1[idx - 8] = hh; l1[idx - 8] = ll; }
        }
    }
    s += __shfl_xor(s, 1);
    s += __shfl_xor(s, 2);
    if (q == 0) nrm[row] = s;

    const int tt = row >> 5, lr = row & 31;
    const long fbase = (long)(tt * 4 + q) * 512;
    *reinterpret_cast<u16x8*>(hi + fbase + lr * 8)        = h0;
    *reinterpret_cast<u16x8*>(hi + fbase + (32 + lr) * 8) = h1;
    *reinterpret_cast<u16x8*>(lo + fbase + lr * 8)        = l0;
    *reinterpret_cast<u16x8*>(lo + fbase + (32 + lr) * 8) = l1;
}

// ============ main: R5 structure + QUADRANT-FUSED epilogue ============
// 4096 blocks x 256 threads (4 waves), 64 KB LDS, 2 blocks/CU.
// Per quadrant: ds_read b-frags -> 12 MFMA -> 16 exp + 16 NT stores.
// Stores of quadrant q overlap MFMAs of q+1 -> store pipe fed continuously.
__global__ __launch_bounds__(256, 2)
void rbf_fused_kernel(const u16* __restrict__ XhiF, const u16* __restrict__ XloF,
                      const u16* __restrict__ YhiF, const u16* __restrict__ YloF,
                      const float* __restrict__ xqs, const float* __restrict__ yqs,
                      const float* __restrict__ gamma_p,
                      float* __restrict__ out)
{
    __shared__ __align__(16) u16 S[4][8192];   // Xhi | Xlo | Yhi | Ylo panels

    const int t = threadIdx.x;
    const int w = t >> 6;
    const int l = t & 63;
    const int loff = l * 8;

    // bijective XCD swizzle: contiguous bm stripes per XCD
    const int bid = blockIdx.x;
    const int swz = ((bid & 7) << 9) | (bid >> 3);
    const int bm = swz >> 6;
    const int bn = swz & 63;
    const long row0 = (long)bm * 128;
    const long col0 = (long)bn * 128;

    // ---- async stage: wave w copies its 16 KB panel via global_load_lds ----
    {
        const u16* gsrc;
        if      (w == 0) gsrc = XhiF + (long)bm * 8192;
        else if (w == 1) gsrc = XloF + (long)bm * 8192;
        else if (w == 2) gsrc = YhiF + (long)bn * 8192;
        else             gsrc = YloF + (long)bn * 8192;
        #pragma unroll
        for (int c = 0; c < 16; ++c)
            load_lds_16B(gsrc + c * 512 + loff, &S[w][c * 512]);
    }

    // hoisted epilogue constants + xq loads (overlap with staging latency)
    const float g  = gamma_p[0];
    const float g2 = 2.0f * g;
    const int  mt0 = (w >> 1) * 2;
    const int  nt0 = (w & 1) * 2;
    const int l5x4 = (l >> 5) * 4;
    const int  ln  = l & 31;

    float xv[2][16];
    #pragma unroll
    for (int ii = 0; ii < 2; ++ii)
        #pragma unroll
        for (int q4 = 0; q4 < 4; ++q4) {
            const float4 x4 = *reinterpret_cast<const float4*>(
                xqs + row0 + (mt0 + ii) * 32 + 8 * q4 + l5x4);
            xv[ii][q4 * 4 + 0] = x4.x; xv[ii][q4 * 4 + 1] = x4.y;
            xv[ii][q4 * 4 + 2] = x4.z; xv[ii][q4 * 4 + 3] = x4.w;
        }
    float cy[2];
    #pragma unroll
    for (int jj = 0; jj < 2; ++jj)
        cy[jj] = -g * yqs[col0 + (nt0 + jj) * 32 + ln];

    __syncthreads();   // staging (vmcnt) drained by barrier semantics

    // a-frags -> registers once (used by all quadrants)
    bf16x8 aH[2][4], aL[2][4];
    #pragma unroll
    for (int ii = 0; ii < 2; ++ii)
        #pragma unroll
        for (int ks = 0; ks < 4; ++ks) {
            aH[ii][ks] = *reinterpret_cast<const bf16x8*>(&S[0][((mt0 + ii) * 4 + ks) * 512 + loff]);
            aL[ii][ks] = *reinterpret_cast<const bf16x8*>(&S[1][((mt0 + ii) * 4 + ks) * 512 + loff]);
        }

    // ---- quadrant-major: compute + store each 32x32 quadrant in turn ----
    // order (ii,jj): (0,0) (1,0) (0,1) (1,1)
    #pragma unroll
    for (int qq = 0; qq < 4; ++qq) {
        const int ii = qq & 1;
        const int jj = qq >> 1;

        // b-frags for this quadrant (lane-linear, conflict-free ds_read_b128)
        bf16x8 bH[4], bL[4];
        #pragma unroll
        for (int ks = 0; ks < 4; ++ks) {
            bH[ks] = *reinterpret_cast<const bf16x8*>(&S[2][((nt0 + jj) * 4 + ks) * 512 + loff]);
            bL[ks] = *reinterpret_cast<const bf16x8*>(&S[3][((nt0 + jj) * 4 + ks) * 512 + loff]);
        }

        f32x16 acc;
        #pragma unroll
        for (int r = 0; r < 16; ++r) acc[r] = 0.f;
        #pragma unroll
        for (int ks = 0; ks < 4; ++ks) {
            acc = MFMA(aH[ii][ks], bH[ks], acc);
            acc = MFMA(aH[ii][ks], bL[ks], acc);
            acc = MFMA(aL[ii][ks], bH[ks], acc);
        }

        // fused epilogue: arg = -g*(xq+yq-2*dot) clamped <= 0; NT-store exp
        // C/D (verified): m-row = (r&3)+8*(r>>2)+l5x4 [+mt*32], n-col = ln [+nt*32]
        const int  mt  = mt0 + ii;
        const long gc  = col0 + (nt0 + jj) * 32 + ln;
        float* const orow = out + (row0 + mt * 32) * (long)NTOT + gc;
        const float cyj = cy[jj];
        #pragma unroll
        for (int r = 0; r < 16; ++r) {
            float arg = fmaf(g2, acc[r], fmaf(-g, xv[ii][r], cyj));
            arg = fminf(arg, 0.f);
            const int rr = (r & 3) + 8 * (r >> 2) + l5x4;
            __builtin_nontemporal_store(__expf(arg), orow + rr * (long)NTOT);
        }
    }
}

// ============ fallback (R2-style, known-good) if ws too small ============
__global__ __launch_bounds__(256, 2)
void rbf_fallback_kernel(const float* __restrict__ X,
                         const float* __restrict__ Y,
                         const float* __restrict__ gamma_p,
                         float* __restrict__ out)
{
    __shared__ unsigned short XfH[4][4][64][8];
    __shared__ unsigned short XfL[4][4][64][8];
    __shared__ unsigned short YfH[4][4][64][8];
    __shared__ unsigned short YfL[4][4][64][8];
    __shared__ float xq[128];
    __shared__ float yq[128];

    const int t = threadIdx.x;
    const long row0 = (long)blockIdx.y * 128;
    const long col0 = (long)blockIdx.x * 128;

    {
        const int k0   = (t & 15) * 4;
        const int ks   = k0 >> 4;
        const int l32  = ((k0 >> 3) & 1) << 5;
        const int slot = k0 & 4;
        #pragma unroll
        for (int i = 0; i < 8; ++i) {
            const int row  = (t >> 4) + i * 16;
            const int mt   = row >> 5;
            const int lane = (row & 31) | l32;
            const float4 vx = *reinterpret_cast<const float4*>(X + (row0 + row) * DD + k0);
            const float4 vy = *reinterpret_cast<const float4*>(Y + (col0 + row) * DD + k0);
            float xv[4] = {vx.x, vx.y, vx.z, vx.w};
            float yv[4] = {vy.x, vy.y, vy.z, vy.w};
            u16x4 xh, xl, yh, yl;
            #pragma unroll
            for (int e = 0; e < 4; ++e) {
                const u16 hx = bf16_rne(xv[e]);
                xh[e] = hx; xl[e] = bf16_rne(xv[e] - bf16_to_f32(hx));
                const u16 hy = bf16_rne(yv[e]);
                yh[e] = hy; yl[e] = bf16_rne(yv[e] - bf16_to_f32(hy));
            }
            *reinterpret_cast<u16x4*>(&XfH[mt][ks][lane][slot]) = xh;
            *reinterpret_cast<u16x4*>(&XfL[mt][ks][lane][slot]) = xl;
            *reinterpret_cast<u16x4*>(&YfH[mt][ks][lane][slot]) = yh;
            *reinterpret_cast<u16x4*>(&YfL[mt][ks][lane][slot]) = yl;
        }
    }
    {
        const int r = t & 127;
        const float* p2 = (t < 128) ? (X + (row0 + r) * DD) : (Y + (col0 + r) * DD);
        float s0 = 0.f, s1 = 0.f, s2 = 0.f, s3 = 0.f;
        #pragma unroll
        for (int c = 0; c < 16; ++c) {
            const float4 v = reinterpret_cast<const float4*>(p2)[c];
            s0 = fmaf(v.x, v.x, s0); s1 = fmaf(v.y, v.y, s1);
            s2 = fmaf(v.z, v.z, s2); s3 = fmaf(v.w, v.w, s3);
        }
        const float s = (s0 + s1) + (s2 + s3);
        if (t < 128) xq[r] = s; else yq[r] = s;
    }
    __syncthreads();

    const int w = t >> 6;
    const int l = t & 63;
    const int mt0 = (w >> 1) * 2;
    const int nt0 = (w & 1) * 2;

    bf16x8 aH[2][4], aL[2][4];
    #pragma unroll
    for (int i = 0; i < 2; ++i)
        #pragma unroll
        for (int ks = 0; ks < 4; ++ks) {
            aH[i][ks] = *reinterpret_cast<const bf16x8*>(&XfH[mt0 + i][ks][l][0]);
            aL[i][ks] = *reinterpret_cast<const bf16x8*>(&XfL[mt0 + i][ks][l][0]);
        }

    f32x16 acc[2][2];
    #pragma unroll
    for (int i = 0; i < 2; ++i)
        #pragma unroll
        for (int j = 0; j < 2; ++j)
            #pragma unroll
            for (int r = 0; r < 16; ++r) acc[i][j][r] = 0.f;

    #pragma unroll
    for (int ks = 0; ks < 4; ++ks) {
        const bf16x8 b0h = *reinterpret_cast<const bf16x8*>(&YfH[nt0 + 0][ks][l][0]);
        const bf16x8 b1h = *reinterpret_cast<const bf16x8*>(&YfH[nt0 + 1][ks][l][0]);
        const bf16x8 b0l = *reinterpret_cast<const bf16x8*>(&YfL[nt0 + 0][ks][l][0]);
        const bf16x8 b1l = *reinterpret_cast<const bf16x8*>(&YfL[nt0 + 1][ks][l][0]);
        acc[0][0] = MFMA(aH[0][ks], b0h, acc[0][0]);
        acc[0][1] = MFMA(aH[0][ks], b1h, acc[0][1]);
        acc[1][0] = MFMA(aH[1][ks], b0h, acc[1][0]);
        acc[1][1] = MFMA(aH[1][ks], b1h, acc[1][1]);
        acc[0][0] = MFMA(aH[0][ks], b0l, acc[0][0]);
        acc[0][1] = MFMA(aH[0][ks], b1l, acc[0][1]);
        acc[1][0] = MFMA(aH[1][ks], b0l, acc[1][0]);
        acc[1][1] = MFMA(aH[1][ks], b1l, acc[1][1]);
        acc[0][0] = MFMA(aL[0][ks], b0h, acc[0][0]);
        acc[0][1] = MFMA(aL[0][ks], b1h, acc[0][1]);
        acc[1][0] = MFMA(aL[1][ks], b0h, acc[1][0]);
        acc[1][1] = MFMA(aL[1][ks], b1h, acc[1][1]);
    }

    const float g = gamma_p[0];
    const int l5x4 = (l >> 5) * 4;
    const int ln = l & 31;
    #pragma unroll
    for (int i = 0; i < 2; ++i) {
        const int mt = mt0 + i;
        float xv[16];
        #pragma unroll
        for (int r = 0; r < 16; ++r)
            xv[r] = xq[mt * 32 + (r & 3) + 8 * (r >> 2) + l5x4];
        #pragma unroll
        for (int j = 0; j < 2; ++j) {
            const int nt = nt0 + j;
            const float yv = yq[nt * 32 + ln];
            const long gr = row0 + mt * 32;
            const long gc = col0 + nt * 32 + ln;
            #pragma unroll
            for (int r = 0; r < 16; ++r) {
                float s = fmaf(-2.f, acc[i][j][r], xv[r] + yv);
                s = fmaxf(s, 0.f);
                const long rr = gr + (r & 3) + 8 * (r >> 2) + l5x4;
                out[rr * NTOT + gc] = __expf(-g * s);
            }
        }
    }
}

extern "C" void kernel_launch(void* const* d_in, const int* in_sizes, int n_in,
                              void* d_out, int out_size, void* d_ws, size_t ws_size,
                              hipStream_t stream) {
    (void)in_sizes; (void)n_in; (void)out_size;
    const float* X = (const float*)d_in[0];
    const float* Y = (const float*)d_in[1];
    const float* gamma_p = (const float*)d_in[2];
    float* out = (float*)d_out;

    const size_t need = 4 * (size_t)SPLIT * sizeof(u16) + (MTOT + NTOT) * sizeof(float);

    if (ws_size >= need) {
        u16* XhiF = (u16*)d_ws;
        u16* XloF = XhiF + SPLIT;
        u16* YhiF = XloF + SPLIT;
        u16* YloF = YhiF + SPLIT;
        float* xqs = (float*)(YloF + SPLIT);
        float* yqs = xqs + MTOT;
        rbf_pre_kernel<<<256, 256, 0, stream>>>(X, Y, XhiF, XloF, YhiF, YloF, xqs, yqs);
        rbf_fused_kernel<<<4096, 256, 0, stream>>>(XhiF, XloF, YhiF, YloF, xqs, yqs, gamma_p, out);
    } else {
        dim3 grid(NTOT / 128, MTOT / 128);
        rbf_fallback_kernel<<<grid, 256, 0, stream>>>(X, Y, gamma_p, out);
    }
}